// Round 2
// baseline (295.086 us; speedup 1.0000x reference)
//
#include <hip/hip_runtime.h>
#include <hip/hip_bf16.h>
#include <cstdint>
#include <cstddef>

typedef float  f32x4   __attribute__((ext_vector_type(4)));
typedef __bf16 bf16x8  __attribute__((ext_vector_type(8)));
typedef unsigned short ushort8 __attribute__((ext_vector_type(8)));

#define NHEAD 12
#define DMODEL 768
#define HDIM 64
#define BATCH 2
#define NQ 1024
#define NS 4096

__device__ __forceinline__ unsigned short f2bf(float f) {
  unsigned int u = __float_as_uint(f);
  u = (u + 0x7fffu + ((u >> 16) & 1u)) >> 16;   // RNE to bf16
  return (unsigned short)u;
}

// ---------------------------------------------------------------------------
// Y = X @ W^T (+bias).  X: M x K fp32 row-major.  W: N x K fp32 row-major.
// If Yb != nullptr -> write bf16 (ushort). Else write fp32 to Yf with bias.
// Block: 256 threads (4 waves). Tile: 64x64, BK=32.
// Wave w computes rows w*16..w*16+15 of the tile, all 64 cols.
// ---------------------------------------------------------------------------
__global__ __launch_bounds__(256) void gemm_xwt(
    const float* __restrict__ X, const float* __restrict__ W,
    unsigned short* __restrict__ Yb, float* __restrict__ Yf,
    const float* __restrict__ bias, int M, int K, int N)
{
  const int n0   = blockIdx.x * 64;
  const int m0   = blockIdx.y * 64;
  const int t    = threadIdx.x;
  const int lane = t & 63;
  const int wave = t >> 6;

  __shared__ unsigned short As[64][40];   // 64 x 32 bf16, pad->40 (2-way banks max)
  __shared__ unsigned short Bs[64][40];

  f32x4 acc[4] = {};

  const int r_st = t >> 2;           // 0..63 (staging row)
  const int c_st = (t & 3) * 8;      // 0,8,16,24 (staging col)
  const int frow = lane & 15;
  const int kk   = (lane >> 4) * 8;  // k-group within BK=32

  for (int k0 = 0; k0 < K; k0 += 32) {
    __syncthreads();
    {
      const float* xp = &X[(size_t)(m0 + r_st) * K + k0 + c_st];
      float4 v0 = *(const float4*)xp;
      float4 v1 = *(const float4*)(xp + 4);
      ushort8 pv;
      pv[0]=f2bf(v0.x); pv[1]=f2bf(v0.y); pv[2]=f2bf(v0.z); pv[3]=f2bf(v0.w);
      pv[4]=f2bf(v1.x); pv[5]=f2bf(v1.y); pv[6]=f2bf(v1.z); pv[7]=f2bf(v1.w);
      *(ushort8*)&As[r_st][c_st] = pv;

      const float* wp = &W[(size_t)(n0 + r_st) * K + k0 + c_st];
      float4 w0 = *(const float4*)wp;
      float4 w1 = *(const float4*)(wp + 4);
      ushort8 pw;
      pw[0]=f2bf(w0.x); pw[1]=f2bf(w0.y); pw[2]=f2bf(w0.z); pw[3]=f2bf(w0.w);
      pw[4]=f2bf(w1.x); pw[5]=f2bf(w1.y); pw[6]=f2bf(w1.z); pw[7]=f2bf(w1.w);
      *(ushort8*)&Bs[r_st][c_st] = pw;
    }
    __syncthreads();

    bf16x8 a = *(const bf16x8*)&As[wave * 16 + frow][kk];
    #pragma unroll
    for (int j = 0; j < 4; ++j) {
      bf16x8 b = *(const bf16x8*)&Bs[j * 16 + frow][kk];
      acc[j] = __builtin_amdgcn_mfma_f32_16x16x32_bf16(a, b, acc[j], 0, 0, 0);
    }
  }

  // C/D layout: col = lane&15, row = (lane>>4)*4 + reg   [m89-verified]
  #pragma unroll
  for (int j = 0; j < 4; ++j) {
    #pragma unroll
    for (int rr = 0; rr < 4; ++rr) {
      const int row = m0 + wave * 16 + (lane >> 4) * 4 + rr;
      const int col = n0 + j * 16 + frow;
      const float v = acc[j][rr];
      if (Yb) Yb[(size_t)row * N + col] = f2bf(v);
      else    Yf[(size_t)row * N + col] = v + bias[col];
    }
  }
}

// ---------------------------------------------------------------------------
// Flash attention over bf16 Q/K/V (already projected, laid out (B*rows, 768)).
// grid: (NQ/64, NHEAD, BATCH); block 256 = 4 waves, wave w owns 16 q-rows.
// Masked columns get score -1e4 (equivalent to reference: exp underflows to 0).
// ---------------------------------------------------------------------------
__global__ __launch_bounds__(256) void attn_fwd(
    const unsigned short* __restrict__ Qb,
    const unsigned short* __restrict__ Kb,
    const unsigned short* __restrict__ Vb,
    const float* __restrict__ mask,
    float* __restrict__ AO)
{
  const int qt   = blockIdx.x;
  const int h    = blockIdx.y;
  const int b    = blockIdx.z;
  const int t    = threadIdx.x;
  const int lane = t & 63;
  const int wave = t >> 6;

  __shared__ unsigned short Qs[64][72];       // 64 q-rows x 64 dims
  __shared__ unsigned short Ks[64][72];       // 64 kv-rows x 64 dims
  __shared__ unsigned short Vt[64][72];       // transposed: Vt[dim][kv-row]
  __shared__ unsigned short Ps[4][16][72];    // per-wave P tile 16 x 64
  __shared__ float msk[64];

  const int r_st = t >> 2;            // 0..63
  const int c_st = (t & 3) * 16;      // 0,16,32,48
  const int frow = lane & 15;
  const int kk   = (lane >> 4) * 8;

  { // load Q tile once
    const uint4* src = (const uint4*)&Qb[((size_t)(b * NQ + qt * 64 + r_st)) * DMODEL + h * HDIM + c_st];
    *(uint4*)&Qs[r_st][c_st]     = src[0];
    *(uint4*)&Qs[r_st][c_st + 8] = src[1];
  }

  float m_r[4], l_r[4];
  f32x4 oacc[4] = {};
  #pragma unroll
  for (int r = 0; r < 4; ++r) { m_r[r] = -INFINITY; l_r[r] = 0.f; }

  for (int s0 = 0; s0 < NS; s0 += 64) {
    __syncthreads();
    { // stage K chunk, V chunk (transposed), mask chunk
      const uint4* ksrc = (const uint4*)&Kb[((size_t)(b * NS + s0 + r_st)) * DMODEL + h * HDIM + c_st];
      *(uint4*)&Ks[r_st][c_st]     = ksrc[0];
      *(uint4*)&Ks[r_st][c_st + 8] = ksrc[1];
      const uint4* vsrc = (const uint4*)&Vb[((size_t)(b * NS + s0 + r_st)) * DMODEL + h * HDIM + c_st];
      union { uint4 q[2]; unsigned short u[16]; } un;
      un.q[0] = vsrc[0]; un.q[1] = vsrc[1];
      #pragma unroll
      for (int e = 0; e < 16; ++e) Vt[c_st + e][r_st] = un.u[e];
      if (t < 64) msk[t] = mask[(size_t)b * NS + s0 + t];
    }
    __syncthreads();

    // ---- scores = Q Kt : 16x64 per wave (4 col-subtiles x 2 k-steps) ----
    f32x4 sacc[4] = {};
    {
      bf16x8 a0 = *(const bf16x8*)&Qs[wave * 16 + frow][kk];
      bf16x8 a1 = *(const bf16x8*)&Qs[wave * 16 + frow][32 + kk];
      #pragma unroll
      for (int j = 0; j < 4; ++j) {
        bf16x8 b0 = *(const bf16x8*)&Ks[j * 16 + frow][kk];
        sacc[j] = __builtin_amdgcn_mfma_f32_16x16x32_bf16(a0, b0, sacc[j], 0, 0, 0);
        bf16x8 b1 = *(const bf16x8*)&Ks[j * 16 + frow][32 + kk];
        sacc[j] = __builtin_amdgcn_mfma_f32_16x16x32_bf16(a1, b1, sacc[j], 0, 0, 0);
      }
    }

    // ---- masked online softmax. score element: row (lane>>4)*4+r, col j*16+frow
    float p[4][4];
    float rmax[4] = {-INFINITY, -INFINITY, -INFINITY, -INFINITY};
    #pragma unroll
    for (int j = 0; j < 4; ++j) {
      const float addm = 10000.0f * msk[j * 16 + frow] - 10000.0f;
      #pragma unroll
      for (int r = 0; r < 4; ++r) {
        const float s = sacc[j][r] * 0.125f + addm;
        p[j][r] = s;
        rmax[r] = fmaxf(rmax[r], s);
      }
    }
    #pragma unroll
    for (int r = 0; r < 4; ++r) {   // max across the 16 lanes holding the row
      rmax[r] = fmaxf(rmax[r], __shfl_xor(rmax[r], 1));
      rmax[r] = fmaxf(rmax[r], __shfl_xor(rmax[r], 2));
      rmax[r] = fmaxf(rmax[r], __shfl_xor(rmax[r], 4));
      rmax[r] = fmaxf(rmax[r], __shfl_xor(rmax[r], 8));
    }
    float sf[4];
    #pragma unroll
    for (int r = 0; r < 4; ++r) {
      const float mnew = fmaxf(m_r[r], rmax[r]);
      sf[r] = __expf(m_r[r] - mnew);   // exp(-inf)=0 on first chunk
      m_r[r] = mnew;
    }
    float rs[4] = {0.f, 0.f, 0.f, 0.f};
    #pragma unroll
    for (int j = 0; j < 4; ++j) {
      #pragma unroll
      for (int r = 0; r < 4; ++r) {
        const float e = __expf(p[j][r] - m_r[r]);
        p[j][r] = e;
        rs[r] += e;
      }
    }
    #pragma unroll
    for (int r = 0; r < 4; ++r) {
      rs[r] += __shfl_xor(rs[r], 1);
      rs[r] += __shfl_xor(rs[r], 2);
      rs[r] += __shfl_xor(rs[r], 4);
      rs[r] += __shfl_xor(rs[r], 8);
      l_r[r] = l_r[r] * sf[r] + rs[r];
    }
    #pragma unroll
    for (int j = 0; j < 4; ++j)
      #pragma unroll
      for (int r = 0; r < 4; ++r)
        oacc[j][r] *= sf[r];

    // ---- P -> LDS (bf16) in A-fragment-friendly row-major layout ----
    #pragma unroll
    for (int j = 0; j < 4; ++j)
      #pragma unroll
      for (int r = 0; r < 4; ++r)
        Ps[wave][(lane >> 4) * 4 + r][j * 16 + frow] = f2bf(p[j][r]);
    __syncthreads();

    // ---- O += P V : A = Ps (16x64), B = V chunk via Vt (contiguous k) ----
    {
      bf16x8 a0 = *(const bf16x8*)&Ps[wave][frow][kk];
      bf16x8 a1 = *(const bf16x8*)&Ps[wave][frow][32 + kk];
      #pragma unroll
      for (int j = 0; j < 4; ++j) {
        bf16x8 b0 = *(const bf16x8*)&Vt[j * 16 + frow][kk];
        oacc[j] = __builtin_amdgcn_mfma_f32_16x16x32_bf16(a0, b0, oacc[j], 0, 0, 0);
        bf16x8 b1 = *(const bf16x8*)&Vt[j * 16 + frow][32 + kk];
        oacc[j] = __builtin_amdgcn_mfma_f32_16x16x32_bf16(a1, b1, oacc[j], 0, 0, 0);
      }
    }
  }

  // ---- epilogue: normalize and write attention output (fp32) ----
  #pragma unroll
  for (int j = 0; j < 4; ++j) {
    #pragma unroll
    for (int r = 0; r < 4; ++r) {
      const int row = qt * 64 + wave * 16 + (lane >> 4) * 4 + r;
      const int col = h * HDIM + j * 16 + frow;
      AO[((size_t)(b * NQ + row)) * DMODEL + col] = oacc[j][r] / l_r[r];
    }
  }
}

// ---------------------------------------------------------------------------
extern "C" void kernel_launch(void* const* d_in, const int* in_sizes, int n_in,
                              void* d_out, int out_size, void* d_ws, size_t ws_size,
                              hipStream_t stream)
{
  const float* query = (const float*)d_in[0];
  const float* key   = (const float*)d_in[1];
  const float* value = (const float*)d_in[2];
  const float* mask  = (const float*)d_in[3];
  const float* Wq    = (const float*)d_in[4];
  const float* Wk    = (const float*)d_in[5];
  const float* Wv    = (const float*)d_in[6];
  const float* Wo    = (const float*)d_in[7];
  const float* bo    = (const float*)d_in[8];
  float* out = (float*)d_out;

  char* ws = (char*)d_ws;
  // workspace layout (bytes):
  //   Qb  bf16 2048*768          @ 0          (3,145,728)
  //   Kb  bf16 8192*768          @ 3145728    (12,582,912)
  //   Vb  bf16 8192*768          @ 15728640   (12,582,912)
  //   AO  fp32 2048*768          @ 28311552   (6,291,456)   total 34,603,008 B
  unsigned short* Qb = (unsigned short*)(ws);
  unsigned short* Kb = (unsigned short*)(ws + 3145728);
  unsigned short* Vb = (unsigned short*)(ws + 15728640);
  float*          AO = (float*)(ws + 28311552);

  const dim3 blk(256);
  // projections (bf16 out)
  gemm_xwt<<<dim3(DMODEL / 64, (BATCH * NQ) / 64), blk, 0, stream>>>(
      query, Wq, Qb, nullptr, nullptr, BATCH * NQ, DMODEL, DMODEL);
  gemm_xwt<<<dim3(DMODEL / 64, (BATCH * NS) / 64), blk, 0, stream>>>(
      key, Wk, Kb, nullptr, nullptr, BATCH * NS, DMODEL, DMODEL);
  gemm_xwt<<<dim3(DMODEL / 64, (BATCH * NS) / 64), blk, 0, stream>>>(
      value, Wv, Vb, nullptr, nullptr, BATCH * NS, DMODEL, DMODEL);
  // attention
  attn_fwd<<<dim3(NQ / 64, NHEAD, BATCH), blk, 0, stream>>>(Qb, Kb, Vb, mask, AO);
  // output projection (fp32 out + bias)
  gemm_xwt<<<dim3(DMODEL / 64, (BATCH * NQ) / 64), blk, 0, stream>>>(
      AO, Wo, nullptr, out, bo, BATCH * NQ, DMODEL, DMODEL);
}

// Round 4
// 223.467 us; speedup vs baseline: 1.3205x; 1.3205x over previous
//
#include <hip/hip_runtime.h>
#include <hip/hip_bf16.h>
#include <cstdint>
#include <cstddef>

typedef float  f32x4   __attribute__((ext_vector_type(4)));
typedef __bf16 bf16x8  __attribute__((ext_vector_type(8)));
typedef unsigned short ushort8 __attribute__((ext_vector_type(8)));
typedef unsigned short ushort4_ __attribute__((ext_vector_type(4)));

#define NHEAD 12
#define DMODEL 768
#define HDIM 64
#define BATCH 2
#define NQ 1024
#define NS 4096
#define BH (BATCH * NHEAD)   // 24

__device__ __forceinline__ unsigned short f2bf(float f) {
  unsigned int u = __float_as_uint(f);
  u = (u + 0x7fffu + ((u >> 16) & 1u)) >> 16;   // RNE to bf16
  return (unsigned short)u;
}

// ---------------------------------------------------------------------------
// Y = X @ W^T (+bias).  X: M x K fp32 row-major.  W: N x K fp32 row-major.
// Output modes: Yb  -> bf16 row-major [M][N]
//               YbT -> bf16 per-head transposed  VtG[b][h][d][kv]  (V proj)
//               Yf  -> fp32 row-major with bias
// Block: 256 threads (4 waves). Tile 64x64, BK=32.
// ---------------------------------------------------------------------------
__global__ __launch_bounds__(256) void gemm_xwt(
    const float* __restrict__ X, const float* __restrict__ W,
    unsigned short* __restrict__ Yb, unsigned short* __restrict__ YbT,
    float* __restrict__ Yf, const float* __restrict__ bias,
    int M, int K, int N)
{
  const int n0   = blockIdx.x * 64;
  const int m0   = blockIdx.y * 64;
  const int t    = threadIdx.x;
  const int lane = t & 63;
  const int wave = t >> 6;

  __shared__ unsigned short As[64][40];
  __shared__ unsigned short Bs[64][40];

  f32x4 acc[4] = {};

  const int r_st = t >> 2;
  const int c_st = (t & 3) * 8;
  const int frow = lane & 15;
  const int kk   = (lane >> 4) * 8;

  for (int k0 = 0; k0 < K; k0 += 32) {
    __syncthreads();
    {
      const float* xp = &X[(size_t)(m0 + r_st) * K + k0 + c_st];
      float4 v0 = *(const float4*)xp;
      float4 v1 = *(const float4*)(xp + 4);
      ushort8 pv;
      pv[0]=f2bf(v0.x); pv[1]=f2bf(v0.y); pv[2]=f2bf(v0.z); pv[3]=f2bf(v0.w);
      pv[4]=f2bf(v1.x); pv[5]=f2bf(v1.y); pv[6]=f2bf(v1.z); pv[7]=f2bf(v1.w);
      *(ushort8*)&As[r_st][c_st] = pv;

      const float* wp = &W[(size_t)(n0 + r_st) * K + k0 + c_st];
      float4 w0 = *(const float4*)wp;
      float4 w1 = *(const float4*)(wp + 4);
      ushort8 pw;
      pw[0]=f2bf(w0.x); pw[1]=f2bf(w0.y); pw[2]=f2bf(w0.z); pw[3]=f2bf(w0.w);
      pw[4]=f2bf(w1.x); pw[5]=f2bf(w1.y); pw[6]=f2bf(w1.z); pw[7]=f2bf(w1.w);
      *(ushort8*)&Bs[r_st][c_st] = pw;
    }
    __syncthreads();

    bf16x8 a = *(const bf16x8*)&As[wave * 16 + frow][kk];
    #pragma unroll
    for (int j = 0; j < 4; ++j) {
      bf16x8 b = *(const bf16x8*)&Bs[j * 16 + frow][kk];
      acc[j] = __builtin_amdgcn_mfma_f32_16x16x32_bf16(a, b, acc[j], 0, 0, 0);
    }
  }

  // C/D layout: col = lane&15, row = (lane>>4)*4 + reg   [m89-verified]
  if (YbT) {
    // V-projection: emit pre-transposed per-head layout VtG[(b*12+h)*64+d][kv].
    // acc[j] regs rr=0..3 are 4 CONSECUTIVE kv rows for one d column -> 8B pack.
    const int row0 = m0 + wave * 16 + (lane >> 4) * 4;  // global kv row of reg 0
    const int bb   = row0 >> 12;                        // / 4096
    const int kv   = row0 & (NS - 1);
    #pragma unroll
    for (int j = 0; j < 4; ++j) {
      ushort4_ pk;
      #pragma unroll
      for (int rr = 0; rr < 4; ++rr) pk[rr] = f2bf(acc[j][rr]);
      const int dg = n0 + j * 16 + frow;   // 0..767
      const int hh = dg >> 6;
      const int dd = dg & 63;
      *(ushort4_*)&YbT[(((size_t)bb * NHEAD + hh) * HDIM + dd) * NS + kv] = pk;
    }
  } else {
    #pragma unroll
    for (int j = 0; j < 4; ++j) {
      #pragma unroll
      for (int rr = 0; rr < 4; ++rr) {
        const int row = m0 + wave * 16 + (lane >> 4) * 4 + rr;
        const int col = n0 + j * 16 + frow;
        const float v = acc[j][rr];
        if (Yb) Yb[(size_t)row * N + col] = f2bf(v);
        else    Yf[(size_t)row * N + col] = v + bias[col];
      }
    }
  }
}

// ---------------------------------------------------------------------------
// Flash attention, KV-split across blocks (flash-decoding style).
// grid: (NQ/64, NHEAD, BATCH*nsplit); block 256 = 4 waves, wave owns 16 q-rows.
// V comes in pre-transposed: VtG[(b*12+h)*64 + d][kv].
// If ml != nullptr: write unnormalized partials Opart + (m,l) per row.
// Else (direct): write normalized AO.
// ---------------------------------------------------------------------------
__global__ __launch_bounds__(256) void attn_fwd(
    const unsigned short* __restrict__ Qb,
    const unsigned short* __restrict__ Kb,
    const unsigned short* __restrict__ VtG,
    const float* __restrict__ mask,
    float* __restrict__ Opart, float* __restrict__ ml,
    float* __restrict__ AO, int nsplit)
{
  const int qt   = blockIdx.x;
  const int h    = blockIdx.y;
  const int b    = blockIdx.z / nsplit;
  const int sp   = blockIdx.z % nsplit;
  const int t    = threadIdx.x;
  const int lane = t & 63;
  const int wave = t >> 6;

  __shared__ unsigned short Qs[64][72];
  __shared__ unsigned short Ks[64][72];
  __shared__ unsigned short Vts[64][72];     // [d][kv] chunk
  __shared__ unsigned short Ps[4][16][72];   // per-wave, wave-private
  __shared__ float msk[64];

  const int r_st = t >> 2;
  const int c_st = (t & 3) * 16;
  const int frow = lane & 15;
  const int kk   = (lane >> 4) * 8;

  { // load Q tile once
    const uint4* src = (const uint4*)&Qb[((size_t)(b * NQ + qt * 64 + r_st)) * DMODEL + h * HDIM + c_st];
    *(uint4*)&Qs[r_st][c_st]     = src[0];
    *(uint4*)&Qs[r_st][c_st + 8] = src[1];
  }

  float m_r[4], l_r[4];
  f32x4 oacc[4] = {};
  #pragma unroll
  for (int r = 0; r < 4; ++r) { m_r[r] = -INFINITY; l_r[r] = 0.f; }

  const int schunks = (NS / 64) / nsplit;
  const int sbase   = sp * schunks * 64;

  for (int it = 0; it < schunks; ++it) {
    const int s0 = sbase + it * 64;
    __syncthreads();
    { // stage K chunk (row-major), Vt chunk (pre-transposed), mask chunk
      const uint4* ksrc = (const uint4*)&Kb[((size_t)(b * NS + s0 + r_st)) * DMODEL + h * HDIM + c_st];
      *(uint4*)&Ks[r_st][c_st]     = ksrc[0];
      *(uint4*)&Ks[r_st][c_st + 8] = ksrc[1];
      const unsigned short* vrow = &VtG[(((size_t)b * NHEAD + h) * HDIM + r_st) * NS + s0 + c_st];
      *(uint4*)&Vts[r_st][c_st]     = *(const uint4*)vrow;
      *(uint4*)&Vts[r_st][c_st + 8] = *(const uint4*)(vrow + 8);
      if (t < 64) msk[t] = mask[(size_t)b * NS + s0 + t];
    }
    __syncthreads();

    // ---- scores = Q Kt : 16x64 per wave ----
    f32x4 sacc[4] = {};
    {
      bf16x8 a0 = *(const bf16x8*)&Qs[wave * 16 + frow][kk];
      bf16x8 a1 = *(const bf16x8*)&Qs[wave * 16 + frow][32 + kk];
      #pragma unroll
      for (int j = 0; j < 4; ++j) {
        bf16x8 b0 = *(const bf16x8*)&Ks[j * 16 + frow][kk];
        sacc[j] = __builtin_amdgcn_mfma_f32_16x16x32_bf16(a0, b0, sacc[j], 0, 0, 0);
        bf16x8 b1 = *(const bf16x8*)&Ks[j * 16 + frow][32 + kk];
        sacc[j] = __builtin_amdgcn_mfma_f32_16x16x32_bf16(a1, b1, sacc[j], 0, 0, 0);
      }
    }

    // ---- masked online softmax (row (lane>>4)*4+r, col j*16+frow) ----
    float p[4][4];
    float rmax[4] = {-INFINITY, -INFINITY, -INFINITY, -INFINITY};
    #pragma unroll
    for (int j = 0; j < 4; ++j) {
      const float addm = 10000.0f * msk[j * 16 + frow] - 10000.0f;
      #pragma unroll
      for (int r = 0; r < 4; ++r) {
        const float s = sacc[j][r] * 0.125f + addm;
        p[j][r] = s;
        rmax[r] = fmaxf(rmax[r], s);
      }
    }
    #pragma unroll
    for (int r = 0; r < 4; ++r) {
      rmax[r] = fmaxf(rmax[r], __shfl_xor(rmax[r], 1));
      rmax[r] = fmaxf(rmax[r], __shfl_xor(rmax[r], 2));
      rmax[r] = fmaxf(rmax[r], __shfl_xor(rmax[r], 4));
      rmax[r] = fmaxf(rmax[r], __shfl_xor(rmax[r], 8));
    }
    float sf[4];
    #pragma unroll
    for (int r = 0; r < 4; ++r) {
      const float mnew = fmaxf(m_r[r], rmax[r]);
      sf[r] = __expf(m_r[r] - mnew);
      m_r[r] = mnew;
    }
    float rs[4] = {0.f, 0.f, 0.f, 0.f};
    #pragma unroll
    for (int j = 0; j < 4; ++j) {
      #pragma unroll
      for (int r = 0; r < 4; ++r) {
        const float e = __expf(p[j][r] - m_r[r]);
        p[j][r] = e;
        rs[r] += e;
      }
    }
    #pragma unroll
    for (int r = 0; r < 4; ++r) {
      rs[r] += __shfl_xor(rs[r], 1);
      rs[r] += __shfl_xor(rs[r], 2);
      rs[r] += __shfl_xor(rs[r], 4);
      rs[r] += __shfl_xor(rs[r], 8);
      l_r[r] = l_r[r] * sf[r] + rs[r];
    }
    #pragma unroll
    for (int j = 0; j < 4; ++j)
      #pragma unroll
      for (int r = 0; r < 4; ++r)
        oacc[j][r] *= sf[r];

    // ---- P -> wave-private LDS (no barrier needed: same-wave RAW) ----
    #pragma unroll
    for (int j = 0; j < 4; ++j)
      #pragma unroll
      for (int r = 0; r < 4; ++r)
        Ps[wave][(lane >> 4) * 4 + r][j * 16 + frow] = f2bf(p[j][r]);

    // ---- O += P V ----
    {
      bf16x8 a0 = *(const bf16x8*)&Ps[wave][frow][kk];
      bf16x8 a1 = *(const bf16x8*)&Ps[wave][frow][32 + kk];
      #pragma unroll
      for (int j = 0; j < 4; ++j) {
        bf16x8 b0 = *(const bf16x8*)&Vts[j * 16 + frow][kk];
        oacc[j] = __builtin_amdgcn_mfma_f32_16x16x32_bf16(a0, b0, oacc[j], 0, 0, 0);
        bf16x8 b1 = *(const bf16x8*)&Vts[j * 16 + frow][32 + kk];
        oacc[j] = __builtin_amdgcn_mfma_f32_16x16x32_bf16(a1, b1, oacc[j], 0, 0, 0);
      }
    }
  }

  // ---- epilogue ----
  if (ml) {
    const int bh = b * NHEAD + h;
    #pragma unroll
    for (int j = 0; j < 4; ++j) {
      #pragma unroll
      for (int r = 0; r < 4; ++r) {
        const int q = qt * 64 + wave * 16 + (lane >> 4) * 4 + r;
        Opart[(((size_t)sp * BH + bh) * NQ + q) * HDIM + j * 16 + frow] = oacc[j][r];
      }
    }
    if (frow == 0) {
      #pragma unroll
      for (int r = 0; r < 4; ++r) {
        const int q = qt * 64 + wave * 16 + (lane >> 4) * 4 + r;
        const size_t mo = (((size_t)sp * BH + bh) * NQ + q) * 2;
        ml[mo]     = m_r[r];
        ml[mo + 1] = l_r[r];
      }
    }
  } else {
    #pragma unroll
    for (int j = 0; j < 4; ++j) {
      #pragma unroll
      for (int r = 0; r < 4; ++r) {
        const int row = qt * 64 + wave * 16 + (lane >> 4) * 4 + r;
        const int col = h * HDIM + j * 16 + frow;
        AO[((size_t)(b * NQ + row)) * DMODEL + col] = oacc[j][r] / l_r[r];
      }
    }
  }
}

// ---------------------------------------------------------------------------
// Combine KV-split partials -> AO (fp32, attention output in [B*NQ][768]).
// grid: B*H*NQ/4 blocks; block = 4 rows x 64 lanes.
// ---------------------------------------------------------------------------
__global__ __launch_bounds__(256) void attn_combine(
    const float* __restrict__ Opart, const float* __restrict__ ml,
    float* __restrict__ AO, int nsplit)
{
  const int row = blockIdx.x * 4 + (threadIdx.x >> 6);   // 0 .. 24575
  const int d   = threadIdx.x & 63;
  const int bh  = row >> 10;
  const int q   = row & (NQ - 1);

  float M = -INFINITY;
  for (int s = 0; s < nsplit; ++s)
    M = fmaxf(M, ml[(((size_t)s * BH + bh) * NQ + q) * 2]);

  float L = 0.f, acc = 0.f;
  for (int s = 0; s < nsplit; ++s) {
    const size_t mo = (((size_t)s * BH + bh) * NQ + q) * 2;
    const float w = __expf(ml[mo] - M);
    L   += w * ml[mo + 1];
    acc += w * Opart[(((size_t)s * BH + bh) * NQ + q) * HDIM + d];
  }
  const int bb = bh / NHEAD, hh = bh % NHEAD;
  AO[((size_t)(bb * NQ + q)) * DMODEL + hh * HDIM + d] = acc / L;
}

// ---------------------------------------------------------------------------
extern "C" void kernel_launch(void* const* d_in, const int* in_sizes, int n_in,
                              void* d_out, int out_size, void* d_ws, size_t ws_size,
                              hipStream_t stream)
{
  const float* query = (const float*)d_in[0];
  const float* key   = (const float*)d_in[1];
  const float* value = (const float*)d_in[2];
  const float* mask  = (const float*)d_in[3];
  const float* Wq    = (const float*)d_in[4];
  const float* Wk    = (const float*)d_in[5];
  const float* Wv    = (const float*)d_in[6];
  const float* Wo    = (const float*)d_in[7];
  const float* bo    = (const float*)d_in[8];
  float* out = (float*)d_out;

  char* ws = (char*)d_ws;
  // workspace layout (bytes):
  //   Qb   bf16 2048*768           @ 0           (3,145,728)
  //   Kb   bf16 8192*768           @ 3,145,728   (12,582,912)
  //   VtG  bf16 24*64*4096         @ 15,728,640  (12,582,912)
  //   AO   fp32 2048*768           @ 28,311,552  (6,291,456)
  //   ml   fp32 nsplit*24*1024*2   @ 34,603,008  (reserve 4 splits: 786,432)
  //   Opart fp32 nsplit*24*1024*64 @ 35,389,440  (nsplit * 6,291,456)
  const size_t OFF_KB = 3145728, OFF_VT = 15728640, OFF_AO = 28311552;
  const size_t OFF_ML = 34603008, OFF_OP = 35389440;
  unsigned short* Qb  = (unsigned short*)(ws);
  unsigned short* Kb  = (unsigned short*)(ws + OFF_KB);
  unsigned short* VtG = (unsigned short*)(ws + OFF_VT);
  float*          AO  = (float*)(ws + OFF_AO);
  float*          mlp = (float*)(ws + OFF_ML);
  float*          Op  = (float*)(ws + OFF_OP);

  // choose split factor by available scratch (deterministic: ws_size is fixed)
  int nsplit = 0;                                     // 0 => direct, no partials
  if      (ws_size >= OFF_OP + 4ull * 6291456ull) nsplit = 4;
  else if (ws_size >= OFF_OP + 2ull * 6291456ull) nsplit = 2;
  else if (ws_size >= OFF_OP + 1ull * 6291456ull) nsplit = 1;

  const dim3 blk(256);
  gemm_xwt<<<dim3(DMODEL / 64, (BATCH * NQ) / 64), blk, 0, stream>>>(
      query, Wq, Qb, nullptr, nullptr, nullptr, BATCH * NQ, DMODEL, DMODEL);
  gemm_xwt<<<dim3(DMODEL / 64, (BATCH * NS) / 64), blk, 0, stream>>>(
      key, Wk, Kb, nullptr, nullptr, nullptr, BATCH * NS, DMODEL, DMODEL);
  gemm_xwt<<<dim3(DMODEL / 64, (BATCH * NS) / 64), blk, 0, stream>>>(
      value, Wv, nullptr, VtG, nullptr, nullptr, BATCH * NS, DMODEL, DMODEL);

  if (nsplit > 0) {
    attn_fwd<<<dim3(NQ / 64, NHEAD, BATCH * nsplit), blk, 0, stream>>>(
        Qb, Kb, VtG, mask, Op, mlp, nullptr, nsplit);
    attn_combine<<<dim3((BH * NQ) / 4), blk, 0, stream>>>(Op, mlp, AO, nsplit);
  } else {
    attn_fwd<<<dim3(NQ / 64, NHEAD, BATCH), blk, 0, stream>>>(
        Qb, Kb, VtG, mask, nullptr, nullptr, AO, 1);
  }

  gemm_xwt<<<dim3(DMODEL / 64, (BATCH * NQ) / 64), blk, 0, stream>>>(
      AO, Wo, nullptr, nullptr, out, bo, BATCH * NQ, DMODEL, DMODEL);
}

// Round 6
// 220.716 us; speedup vs baseline: 1.3369x; 1.0125x over previous
//
#include <hip/hip_runtime.h>
#include <hip/hip_bf16.h>
#include <cstdint>
#include <cstddef>

typedef float  f32x4   __attribute__((ext_vector_type(4)));
typedef __bf16 bf16x8  __attribute__((ext_vector_type(8)));
typedef __bf16 bf16x4  __attribute__((ext_vector_type(4)));

#define NHEAD 12
#define DMODEL 768
#define HDIM 64
#define BATCH 2
#define NQ 1024
#define NS 4096
#define BH 24
#define KDIM 768
#define LOG2E 1.4426950408889634f

__device__ __forceinline__ void gll16(const void* g, void* l) {
  __builtin_amdgcn_global_load_lds(
      (const __attribute__((address_space(1))) void*)g,
      (__attribute__((address_space(3))) void*)l, 16, 0, 0);
}

// ---------------------------------------------------------------------------
// Convert the 4 weight matrices (768x768 fp32) to bf16, packed consecutively.
// grid (288, 4), block 256, 8 elems/thread.
// ---------------------------------------------------------------------------
__global__ __launch_bounds__(256) void convw(
    const float* __restrict__ a, const float* __restrict__ b,
    const float* __restrict__ c, const float* __restrict__ d,
    __bf16* __restrict__ o)
{
  const float* s;
  switch (blockIdx.y) { case 0: s = a; break; case 1: s = b; break;
                        case 2: s = c; break; default: s = d; }
  __bf16* dst = o + (size_t)blockIdx.y * (DMODEL * KDIM);
  const int i = (blockIdx.x * 256 + threadIdx.x) * 8;
  const float4 v0 = *(const float4*)&s[i];
  const float4 v1 = *(const float4*)&s[i + 4];
  bf16x8 pk;
  pk[0] = (__bf16)v0.x; pk[1] = (__bf16)v0.y; pk[2] = (__bf16)v0.z; pk[3] = (__bf16)v0.w;
  pk[4] = (__bf16)v1.x; pk[5] = (__bf16)v1.y; pk[6] = (__bf16)v1.z; pk[7] = (__bf16)v1.w;
  *(bf16x8*)&dst[i] = pk;
}

// ---------------------------------------------------------------------------
// Y = X @ W^T (+bias).  W: bf16 [768][768] row-major (pre-converted).
// XBF=0: X fp32 (VGPR-stage + cvt_pk into LDS).  XBF=1: X bf16 (global_load_lds).
// Tile 128x128, BK=64, 256 threads (4 waves, 2x2 of 64x64).
// LDS layout: [row][slot*8] bf16, 128B rows, XOR-swizzled slot ^= (row&7)
// applied identically on fill (pre-swizzled global source / swizzled ds_write)
// and on read -> conflict-free ds_read_b128.
// Out modes: Yb bf16 row-major | YbT = VtG[(b*12+h)*64+d][kv] | Yf fp32+bias.
// ---------------------------------------------------------------------------
template <int XBF>
__global__ __launch_bounds__(256) void gemm128(
    const void* __restrict__ Xv, const __bf16* __restrict__ Wb,
    __bf16* __restrict__ Yb, __bf16* __restrict__ YbT,
    float* __restrict__ Yf, const float* __restrict__ bias, int M)
{
  const int n0   = blockIdx.x * 128;
  const int m0   = blockIdx.y * 128;
  const int t    = threadIdx.x;
  const int lane = t & 63;
  const int wave = t >> 6;
  const int wr   = wave >> 1, wc = wave & 1;
  const int frow = lane & 15, hi = lane >> 4;

  __shared__ __align__(16) __bf16 As[128 * 64];
  __shared__ __align__(16) __bf16 Bs[128 * 64];

  f32x4 acc[4][4] = {};

  const int srow  = t >> 3;   // 0..31
  const int sslot = t & 7;    // 16B slot within 128B row

  for (int k0 = 0; k0 < KDIM; k0 += 64) {
    __syncthreads();
    // --- W tile via global_load_lds (dest linear, source pre-swizzled) ---
    #pragma unroll
    for (int i = 0; i < 4; ++i) {
      const int row = i * 32 + srow;
      const int cs  = (sslot ^ (row & 7)) * 8;
      gll16(&Wb[(size_t)(n0 + row) * KDIM + k0 + cs],
            (char*)Bs + i * 4096 + wave * 1024);
    }
    // --- X tile ---
    if constexpr (XBF) {
      const __bf16* Xb = (const __bf16*)Xv;
      #pragma unroll
      for (int i = 0; i < 4; ++i) {
        const int row = i * 32 + srow;
        const int cs  = (sslot ^ (row & 7)) * 8;
        gll16(&Xb[(size_t)(m0 + row) * KDIM + k0 + cs],
              (char*)As + i * 4096 + wave * 1024);
      }
    } else {
      const float* Xf = (const float*)Xv;
      #pragma unroll
      for (int i = 0; i < 4; ++i) {
        const int row = i * 32 + srow;
        const int cs  = (sslot ^ (row & 7)) * 8;
        const float4 v0 = *(const float4*)&Xf[(size_t)(m0 + row) * KDIM + k0 + cs];
        const float4 v1 = *(const float4*)&Xf[(size_t)(m0 + row) * KDIM + k0 + cs + 4];
        bf16x8 pk;
        pk[0] = (__bf16)v0.x; pk[1] = (__bf16)v0.y; pk[2] = (__bf16)v0.z; pk[3] = (__bf16)v0.w;
        pk[4] = (__bf16)v1.x; pk[5] = (__bf16)v1.y; pk[6] = (__bf16)v1.z; pk[7] = (__bf16)v1.w;
        *(bf16x8*)&As[row * 64 + sslot * 8] = pk;   // linear slot (content pre-swizzled)
      }
    }
    __syncthreads();

    #pragma unroll
    for (int ks = 0; ks < 2; ++ks) {
      bf16x8 af[4], bfr[4];
      #pragma unroll
      for (int mi = 0; mi < 4; ++mi) {
        const int row = wr * 64 + mi * 16 + frow;
        af[mi] = *(const bf16x8*)&As[row * 64 + ((ks * 4 + hi) ^ (frow & 7)) * 8];
      }
      #pragma unroll
      for (int ni = 0; ni < 4; ++ni) {
        const int row = wc * 64 + ni * 16 + frow;
        bfr[ni] = *(const bf16x8*)&Bs[row * 64 + ((ks * 4 + hi) ^ (frow & 7)) * 8];
      }
      #pragma unroll
      for (int mi = 0; mi < 4; ++mi)
        #pragma unroll
        for (int ni = 0; ni < 4; ++ni)
          acc[mi][ni] = __builtin_amdgcn_mfma_f32_16x16x32_bf16(
              af[mi], bfr[ni], acc[mi][ni], 0, 0, 0);
    }
  }

  // ---- epilogue.  C/D: col=lane&15, row=(lane>>4)*4+reg  [m89-verified] ----
  if (YbT) {
    #pragma unroll
    for (int mi = 0; mi < 4; ++mi) {
      const int row0 = m0 + wr * 64 + mi * 16 + hi * 4;  // 4 consecutive kv rows
      const int bb = row0 >> 12;
      const int kv = row0 & (NS - 1);
      #pragma unroll
      for (int ni = 0; ni < 4; ++ni) {
        bf16x4 pk;
        #pragma unroll
        for (int rr = 0; rr < 4; ++rr) pk[rr] = (__bf16)acc[mi][ni][rr];
        const int dg = n0 + wc * 64 + ni * 16 + frow;
        const int hh = dg >> 6, dd = dg & 63;
        *(bf16x4*)&YbT[(((size_t)bb * NHEAD + hh) * HDIM + dd) * NS + kv] = pk;
      }
    }
  } else if (Yb) {
    #pragma unroll
    for (int mi = 0; mi < 4; ++mi)
      #pragma unroll
      for (int ni = 0; ni < 4; ++ni)
        #pragma unroll
        for (int rr = 0; rr < 4; ++rr) {
          const int row = m0 + wr * 64 + mi * 16 + hi * 4 + rr;
          const int col = n0 + wc * 64 + ni * 16 + frow;
          Yb[(size_t)row * DMODEL + col] = (__bf16)acc[mi][ni][rr];
        }
  } else {
    #pragma unroll
    for (int mi = 0; mi < 4; ++mi)
      #pragma unroll
      for (int ni = 0; ni < 4; ++ni) {
        const int col = n0 + wc * 64 + ni * 16 + frow;
        const float bv = bias[col];
        #pragma unroll
        for (int rr = 0; rr < 4; ++rr) {
          const int row = m0 + wr * 64 + mi * 16 + hi * 4 + rr;
          Yf[(size_t)row * DMODEL + col] = acc[mi][ni][rr] + bv;
        }
      }
  }
}

// ---------------------------------------------------------------------------
// Flash attention, KV-split. grid (NQ/64, NHEAD, BATCH*nsplit), 4 waves.
// exp2-domain online softmax (m tracked in log2 units).
// If ml != nullptr: unnormalized partials.  Else: direct bf16 AObf write.
// ---------------------------------------------------------------------------
__global__ __launch_bounds__(256) void attn_fwd(
    const __bf16* __restrict__ Qb, const __bf16* __restrict__ Kb,
    const __bf16* __restrict__ VtG, const float* __restrict__ mask,
    float* __restrict__ Opart, float* __restrict__ ml,
    __bf16* __restrict__ AObf, int nsplit)
{
  const int qt   = blockIdx.x;
  const int h    = blockIdx.y;
  const int b    = blockIdx.z / nsplit;
  const int sp   = blockIdx.z % nsplit;
  const int t    = threadIdx.x;
  const int lane = t & 63;
  const int wave = t >> 6;

  __shared__ unsigned short Qs[64][72];
  __shared__ unsigned short Ks[64][72];
  __shared__ unsigned short Vts[64][72];     // [d][kv]
  __shared__ __align__(16) __bf16 Ps[4][16][72];
  __shared__ float msk[64];

  const int r_st = t >> 2;
  const int c_st = (t & 3) * 16;
  const int frow = lane & 15;
  const int hi   = lane >> 4;
  const int kk   = hi * 8;
  const float C1 = 0.125f * LOG2E;           // SCALE * log2(e)
  const float CM = 10000.0f * LOG2E;

  { // Q tile once
    const uint4* src = (const uint4*)&Qb[((size_t)(b * NQ + qt * 64 + r_st)) * DMODEL + h * HDIM + c_st];
    *(uint4*)&Qs[r_st][c_st]     = src[0];
    *(uint4*)&Qs[r_st][c_st + 8] = src[1];
  }

  float m_r[4], l_r[4];
  f32x4 oacc[4] = {};
  #pragma unroll
  for (int r = 0; r < 4; ++r) { m_r[r] = -INFINITY; l_r[r] = 0.f; }

  const int schunks = (NS / 64) / nsplit;
  const int sbase   = sp * schunks * 64;

  for (int it = 0; it < schunks; ++it) {
    const int s0 = sbase + it * 64;
    __syncthreads();
    {
      const uint4* ksrc = (const uint4*)&Kb[((size_t)(b * NS + s0 + r_st)) * DMODEL + h * HDIM + c_st];
      *(uint4*)&Ks[r_st][c_st]     = ksrc[0];
      *(uint4*)&Ks[r_st][c_st + 8] = ksrc[1];
      const __bf16* vrow = &VtG[(((size_t)b * NHEAD + h) * HDIM + r_st) * NS + s0 + c_st];
      *(uint4*)&Vts[r_st][c_st]     = *(const uint4*)vrow;
      *(uint4*)&Vts[r_st][c_st + 8] = *(const uint4*)(vrow + 8);
      if (t < 64) msk[t] = mask[(size_t)b * NS + s0 + t];
    }
    __syncthreads();

    // ---- scores ----
    f32x4 sacc[4] = {};
    {
      bf16x8 a0 = *(const bf16x8*)&Qs[wave * 16 + frow][kk];
      bf16x8 a1 = *(const bf16x8*)&Qs[wave * 16 + frow][32 + kk];
      #pragma unroll
      for (int j = 0; j < 4; ++j) {
        bf16x8 b0 = *(const bf16x8*)&Ks[j * 16 + frow][kk];
        sacc[j] = __builtin_amdgcn_mfma_f32_16x16x32_bf16(a0, b0, sacc[j], 0, 0, 0);
        bf16x8 b1 = *(const bf16x8*)&Ks[j * 16 + frow][32 + kk];
        sacc[j] = __builtin_amdgcn_mfma_f32_16x16x32_bf16(a1, b1, sacc[j], 0, 0, 0);
      }
    }

    // ---- masked online softmax, log2 domain ----
    float p[4][4];
    float rmax[4] = {-INFINITY, -INFINITY, -INFINITY, -INFINITY};
    #pragma unroll
    for (int j = 0; j < 4; ++j) {
      const float addm = (msk[j * 16 + frow] - 1.0f) * CM;
      #pragma unroll
      for (int r = 0; r < 4; ++r) {
        const float s = sacc[j][r] * C1 + addm;
        p[j][r] = s;
        rmax[r] = fmaxf(rmax[r], s);
      }
    }
    #pragma unroll
    for (int r = 0; r < 4; ++r) {
      rmax[r] = fmaxf(rmax[r], __shfl_xor(rmax[r], 1));
      rmax[r] = fmaxf(rmax[r], __shfl_xor(rmax[r], 2));
      rmax[r] = fmaxf(rmax[r], __shfl_xor(rmax[r], 4));
      rmax[r] = fmaxf(rmax[r], __shfl_xor(rmax[r], 8));
    }
    float sf[4];
    #pragma unroll
    for (int r = 0; r < 4; ++r) {
      const float mnew = fmaxf(m_r[r], rmax[r]);
      sf[r] = exp2f(m_r[r] - mnew);
      m_r[r] = mnew;
    }
    float rs[4] = {0.f, 0.f, 0.f, 0.f};
    #pragma unroll
    for (int j = 0; j < 4; ++j) {
      #pragma unroll
      for (int r = 0; r < 4; ++r) {
        const float e = exp2f(p[j][r] - m_r[r]);
        p[j][r] = e;
        rs[r] += e;
      }
    }
    #pragma unroll
    for (int r = 0; r < 4; ++r) {
      rs[r] += __shfl_xor(rs[r], 1);
      rs[r] += __shfl_xor(rs[r], 2);
      rs[r] += __shfl_xor(rs[r], 4);
      rs[r] += __shfl_xor(rs[r], 8);
      l_r[r] = l_r[r] * sf[r] + rs[r];
    }
    #pragma unroll
    for (int j = 0; j < 4; ++j)
      #pragma unroll
      for (int r = 0; r < 4; ++r)
        oacc[j][r] *= sf[r];

    // ---- P -> wave-private LDS (native cvt; same-wave RAW) ----
    #pragma unroll
    for (int j = 0; j < 4; ++j)
      #pragma unroll
      for (int r = 0; r < 4; ++r)
        Ps[wave][hi * 4 + r][j * 16 + frow] = (__bf16)p[j][r];

    // ---- O += P V ----
    {
      bf16x8 a0 = *(const bf16x8*)&Ps[wave][frow][kk];
      bf16x8 a1 = *(const bf16x8*)&Ps[wave][frow][32 + kk];
      #pragma unroll
      for (int j = 0; j < 4; ++j) {
        bf16x8 b0 = *(const bf16x8*)&Vts[j * 16 + frow][kk];
        oacc[j] = __builtin_amdgcn_mfma_f32_16x16x32_bf16(a0, b0, oacc[j], 0, 0, 0);
        bf16x8 b1 = *(const bf16x8*)&Vts[j * 16 + frow][32 + kk];
        oacc[j] = __builtin_amdgcn_mfma_f32_16x16x32_bf16(a1, b1, oacc[j], 0, 0, 0);
      }
    }
  }

  // ---- epilogue ----
  if (ml) {
    const int bh = b * NHEAD + h;
    #pragma unroll
    for (int j = 0; j < 4; ++j)
      #pragma unroll
      for (int r = 0; r < 4; ++r) {
        const int q = qt * 64 + wave * 16 + hi * 4 + r;
        Opart[(((size_t)sp * BH + bh) * NQ + q) * HDIM + j * 16 + frow] = oacc[j][r];
      }
    if (frow == 0) {
      #pragma unroll
      for (int r = 0; r < 4; ++r) {
        const int q = qt * 64 + wave * 16 + hi * 4 + r;
        const size_t mo = (((size_t)sp * BH + bh) * NQ + q) * 2;
        ml[mo]     = m_r[r];      // log2-domain max
        ml[mo + 1] = l_r[r];
      }
    }
  } else {
    #pragma unroll
    for (int j = 0; j < 4; ++j)
      #pragma unroll
      for (int r = 0; r < 4; ++r) {
        const int row = qt * 64 + wave * 16 + hi * 4 + r;
        const int col = h * HDIM + j * 16 + frow;
        AObf[((size_t)(b * NQ + row)) * DMODEL + col] = (__bf16)(oacc[j][r] / l_r[r]);
      }
  }
}

// ---------------------------------------------------------------------------
// Combine split partials -> AObf (bf16, [B*NQ][768]).  exp2 domain.
// ---------------------------------------------------------------------------
__global__ __launch_bounds__(256) void attn_combine(
    const float* __restrict__ Opart, const float* __restrict__ ml,
    __bf16* __restrict__ AObf, int nsplit)
{
  const int row = blockIdx.x * 4 + (threadIdx.x >> 6);
  const int d   = threadIdx.x & 63;
  const int bh  = row >> 10;
  const int q   = row & (NQ - 1);

  float M = -INFINITY;
  for (int s = 0; s < nsplit; ++s)
    M = fmaxf(M, ml[(((size_t)s * BH + bh) * NQ + q) * 2]);

  float L = 0.f, acc = 0.f;
  for (int s = 0; s < nsplit; ++s) {
    const size_t mo = (((size_t)s * BH + bh) * NQ + q) * 2;
    const float w = exp2f(ml[mo] - M);
    L   += w * ml[mo + 1];
    acc += w * Opart[(((size_t)s * BH + bh) * NQ + q) * HDIM + d];
  }
  const int bb = bh / NHEAD, hh = bh % NHEAD;
  AObf[((size_t)(bb * NQ + q)) * DMODEL + hh * HDIM + d] = (__bf16)(acc / L);
}

// ---------------------------------------------------------------------------
extern "C" void kernel_launch(void* const* d_in, const int* in_sizes, int n_in,
                              void* d_out, int out_size, void* d_ws, size_t ws_size,
                              hipStream_t stream)
{
  const float* query = (const float*)d_in[0];
  const float* key   = (const float*)d_in[1];
  const float* value = (const float*)d_in[2];
  const float* mask  = (const float*)d_in[3];
  const float* Wq    = (const float*)d_in[4];
  const float* Wk    = (const float*)d_in[5];
  const float* Wv    = (const float*)d_in[6];
  const float* Wo    = (const float*)d_in[7];
  const float* bo    = (const float*)d_in[8];
  float* out = (float*)d_out;

  char* ws = (char*)d_ws;
  // workspace layout (bytes):
  //   wb4   bf16 4*768*768      @ 0            (4,718,592)  [Wq|Wk|Wv|Wo]
  //   Qb    bf16 2048*768       @ 4,718,592    (3,145,728)  reused as AObf after attn
  //   Kb    bf16 8192*768       @ 7,864,320    (12,582,912)
  //   VtG   bf16 24*64*4096     @ 20,447,232   (12,582,912)
  //   Op    fp32 ns*24*1024*64  @ 33,030,144   (ns*6,291,456)
  //   ml    fp32 ns*24*1024*2   @ Op+           (ns*196,608)
  const size_t OFF_QB = 4718592, OFF_KB = 7864320, OFF_VT = 20447232, OFF_OP = 33030144;
  __bf16* wb4  = (__bf16*)(ws);
  __bf16* Qb   = (__bf16*)(ws + OFF_QB);
  __bf16* AObf = Qb;                          // alias: Qb dead when AObf written
  __bf16* Kb   = (__bf16*)(ws + OFF_KB);
  __bf16* VtG  = (__bf16*)(ws + OFF_VT);
  float*  Op   = (float*)(ws + OFF_OP);

  int nsplit = 0;
  const size_t per = 6291456ull + 196608ull;
  if      (ws_size >= OFF_OP + 8 * per) nsplit = 8;
  else if (ws_size >= OFF_OP + 4 * per) nsplit = 4;
  else if (ws_size >= OFF_OP + 2 * per) nsplit = 2;
  else if (ws_size >= OFF_OP + 1 * per) nsplit = 1;
  float* mlp = (float*)(ws + OFF_OP + (size_t)nsplit * 6291456ull);

  const dim3 blk(256);
  convw<<<dim3(288, 4), blk, 0, stream>>>(Wq, Wk, Wv, Wo, wb4);

  gemm128<0><<<dim3(6, 16), blk, 0, stream>>>(
      query, wb4 + 0 * 589824, Qb, nullptr, nullptr, nullptr, BATCH * NQ);
  gemm128<0><<<dim3(6, 64), blk, 0, stream>>>(
      key,   wb4 + 1 * 589824, Kb, nullptr, nullptr, nullptr, BATCH * NS);
  gemm128<0><<<dim3(6, 64), blk, 0, stream>>>(
      value, wb4 + 2 * 589824, nullptr, VtG, nullptr, nullptr, BATCH * NS);

  if (nsplit > 0) {
    attn_fwd<<<dim3(NQ / 64, NHEAD, BATCH * nsplit), blk, 0, stream>>>(
        Qb, Kb, VtG, mask, Op, mlp, nullptr, nsplit);
    attn_combine<<<dim3((BH * NQ) / 4), blk, 0, stream>>>(Op, mlp, AObf, nsplit);
  } else {
    attn_fwd<<<dim3(NQ / 64, NHEAD, BATCH), blk, 0, stream>>>(
        Qb, Kb, VtG, mask, nullptr, nullptr, AObf, 1);
  }

  gemm128<1><<<dim3(6, 16), blk, 0, stream>>>(
      AObf, wb4 + 3 * 589824, nullptr, nullptr, out, bo, BATCH * NQ);
}

// Round 8
// 166.089 us; speedup vs baseline: 1.7767x; 1.3289x over previous
//
#include <hip/hip_runtime.h>
#include <hip/hip_bf16.h>
#include <cstdint>
#include <cstddef>

typedef float  f32x4   __attribute__((ext_vector_type(4)));
typedef __bf16 bf16x8  __attribute__((ext_vector_type(8)));
typedef __bf16 bf16x4  __attribute__((ext_vector_type(4)));

#define NHEAD 12
#define DMODEL 768
#define HDIM 64
#define BATCH 2
#define NQ 1024
#define NS 4096
#define BH 24
#define KDIM 768
#define LOG2E 1.4426950408889634f

__device__ __forceinline__ void gll16(const void* g, void* l) {
  __builtin_amdgcn_global_load_lds(
      (const __attribute__((address_space(1))) void*)g,
      (__attribute__((address_space(3))) void*)l, 16, 0, 0);
}

// ---------------------------------------------------------------------------
// fp32 -> bf16 weight conversion, 4 matrices packed consecutively.
// ---------------------------------------------------------------------------
__global__ __launch_bounds__(256) void convw(
    const float* __restrict__ a, const float* __restrict__ b,
    const float* __restrict__ c, const float* __restrict__ d,
    __bf16* __restrict__ o)
{
  const float* s;
  switch (blockIdx.y) { case 0: s = a; break; case 1: s = b; break;
                        case 2: s = c; break; default: s = d; }
  __bf16* dst = o + (size_t)blockIdx.y * (DMODEL * KDIM);
  const int i = (blockIdx.x * 256 + threadIdx.x) * 8;
  const float4 v0 = *(const float4*)&s[i];
  const float4 v1 = *(const float4*)&s[i + 4];
  bf16x8 pk;
  pk[0] = (__bf16)v0.x; pk[1] = (__bf16)v0.y; pk[2] = (__bf16)v0.z; pk[3] = (__bf16)v0.w;
  pk[4] = (__bf16)v1.x; pk[5] = (__bf16)v1.y; pk[6] = (__bf16)v1.z; pk[7] = (__bf16)v1.w;
  *(bf16x8*)&dst[i] = pk;
}

// ---------------------------------------------------------------------------
// fp32 -> bf16 input conversion: query (1.57M), key (6.29M), value (6.29M).
// grid (3072, 3); guard for the smaller query.
// ---------------------------------------------------------------------------
__global__ __launch_bounds__(256) void convx(
    const float* __restrict__ q, const float* __restrict__ k,
    const float* __restrict__ v, __bf16* __restrict__ qo,
    __bf16* __restrict__ ko, __bf16* __restrict__ vo)
{
  const float* s; __bf16* dst; int n;
  switch (blockIdx.y) {
    case 0:  s = q; dst = qo; n = BATCH * NQ * DMODEL; break;
    case 1:  s = k; dst = ko; n = BATCH * NS * DMODEL; break;
    default: s = v; dst = vo; n = BATCH * NS * DMODEL; break;
  }
  const int i = (blockIdx.x * 256 + threadIdx.x) * 8;
  if (i >= n) return;
  const float4 v0 = *(const float4*)&s[i];
  const float4 v1 = *(const float4*)&s[i + 4];
  bf16x8 pk;
  pk[0] = (__bf16)v0.x; pk[1] = (__bf16)v0.y; pk[2] = (__bf16)v0.z; pk[3] = (__bf16)v0.w;
  pk[4] = (__bf16)v1.x; pk[5] = (__bf16)v1.y; pk[6] = (__bf16)v1.z; pk[7] = (__bf16)v1.w;
  *(bf16x8*)&dst[i] = pk;
}

// ---------------------------------------------------------------------------
// Merged Q/K/V projection, all-bf16 (outproj pattern: gll16 both operands).
// grid (6, 144): y<16 -> Q, 16<=y<80 -> K, y>=80 -> V.
// Tile 128x128, BK=64.  LDS XOR-swizzle: linear global + swizzled source
// address on fill + same XOR on frag read (rule-21 consistent; round-6 proven).
// Outputs are LINEAR layouts: Qb/Kb bf16 row-major [row][768]; VtG[bh*64+d][kv].
// ---------------------------------------------------------------------------
__global__ __launch_bounds__(256) void qkvproj(
    const __bf16* __restrict__ Xqb, const __bf16* __restrict__ Xkb,
    const __bf16* __restrict__ Xvb, const __bf16* __restrict__ wb4,
    __bf16* __restrict__ Qb, __bf16* __restrict__ Kb, __bf16* __restrict__ VtG)
{
  const int y = blockIdx.y;
  int mode, m0;
  const __bf16* Xb;
  const __bf16* Wb;
  if (y < 16)      { mode = 0; m0 = y * 128;        Xb = Xqb; Wb = wb4; }
  else if (y < 80) { mode = 1; m0 = (y - 16) * 128; Xb = Xkb; Wb = wb4 + 589824; }
  else             { mode = 2; m0 = (y - 80) * 128; Xb = Xvb; Wb = wb4 + 2 * 589824; }

  const int n0   = blockIdx.x * 128;
  const int t    = threadIdx.x;
  const int lane = t & 63;
  const int wave = t >> 6;
  const int wr   = wave >> 1, wc = wave & 1;
  const int frow = lane & 15, hi = lane >> 4;

  __shared__ __align__(16) __bf16 As[128 * 64];
  __shared__ __align__(16) __bf16 Bs[128 * 64];

  f32x4 acc[4][4] = {};
  const int srow  = t >> 3;
  const int sslot = t & 7;

  for (int k0 = 0; k0 < KDIM; k0 += 64) {
    __syncthreads();
    #pragma unroll
    for (int i = 0; i < 4; ++i) {
      const int row = i * 32 + srow;
      const int cs  = (sslot ^ (row & 7)) * 8;
      gll16(&Wb[(size_t)(n0 + row) * KDIM + k0 + cs],
            (char*)Bs + i * 4096 + wave * 1024);
      gll16(&Xb[(size_t)(m0 + row) * KDIM + k0 + cs],
            (char*)As + i * 4096 + wave * 1024);
    }
    __syncthreads();

    #pragma unroll
    for (int ks = 0; ks < 2; ++ks) {
      bf16x8 af[4], bfr[4];
      #pragma unroll
      for (int mi = 0; mi < 4; ++mi) {
        const int row = wr * 64 + mi * 16 + frow;
        af[mi] = *(const bf16x8*)&As[row * 64 + ((ks * 4 + hi) ^ (frow & 7)) * 8];
      }
      #pragma unroll
      for (int ni = 0; ni < 4; ++ni) {
        const int row = wc * 64 + ni * 16 + frow;
        bfr[ni] = *(const bf16x8*)&Bs[row * 64 + ((ks * 4 + hi) ^ (frow & 7)) * 8];
      }
      #pragma unroll
      for (int mi = 0; mi < 4; ++mi)
        #pragma unroll
        for (int ni = 0; ni < 4; ++ni)
          acc[mi][ni] = __builtin_amdgcn_mfma_f32_16x16x32_bf16(
              af[mi], bfr[ni], acc[mi][ni], 0, 0, 0);
    }
  }

  // C/D: col=lane&15, row=(lane>>4)*4+reg  [m89-verified]
  if (mode == 0) {
    #pragma unroll
    for (int mi = 0; mi < 4; ++mi)
      #pragma unroll
      for (int ni = 0; ni < 4; ++ni)
        #pragma unroll
        for (int rr = 0; rr < 4; ++rr) {
          const int row = m0 + wr * 64 + mi * 16 + hi * 4 + rr;
          const int col = n0 + wc * 64 + ni * 16 + frow;
          Qb[(size_t)row * DMODEL + col] = (__bf16)acc[mi][ni][rr];
        }
  } else if (mode == 1) {
    #pragma unroll
    for (int mi = 0; mi < 4; ++mi)
      #pragma unroll
      for (int ni = 0; ni < 4; ++ni)
        #pragma unroll
        for (int rr = 0; rr < 4; ++rr) {
          const int row = m0 + wr * 64 + mi * 16 + hi * 4 + rr;     // b*NS+kv
          const int col = n0 + wc * 64 + ni * 16 + frow;
          Kb[(size_t)row * DMODEL + col] = (__bf16)acc[mi][ni][rr]; // LINEAR
        }
  } else {
    #pragma unroll
    for (int mi = 0; mi < 4; ++mi) {
      const int row0 = m0 + wr * 64 + mi * 16 + hi * 4;   // 4 consecutive kv
      const int bb = row0 >> 12;
      const int kv = row0 & (NS - 1);
      #pragma unroll
      for (int ni = 0; ni < 4; ++ni) {
        bf16x4 pk;
        #pragma unroll
        for (int rr = 0; rr < 4; ++rr) pk[rr] = (__bf16)acc[mi][ni][rr];
        const int dg = n0 + wc * 64 + ni * 16 + frow;
        const int hh = dg >> 6, dd = dg & 63;
        *(bf16x4*)&VtG[(((size_t)bb * NHEAD + hh) * HDIM + dd) * NS + kv] = pk; // LINEAR
      }
    }
  }
}

// ---------------------------------------------------------------------------
// Out projection: out = AObf @ Wo^T + bo (fp32).
// ---------------------------------------------------------------------------
__global__ __launch_bounds__(256) void outproj(
    const __bf16* __restrict__ Xb, const __bf16* __restrict__ Wb,
    float* __restrict__ Yf, const float* __restrict__ bias)
{
  const int n0   = blockIdx.x * 128;
  const int m0   = blockIdx.y * 128;
  const int t    = threadIdx.x;
  const int lane = t & 63;
  const int wave = t >> 6;
  const int wr   = wave >> 1, wc = wave & 1;
  const int frow = lane & 15, hi = lane >> 4;

  __shared__ __align__(16) __bf16 As[128 * 64];
  __shared__ __align__(16) __bf16 Bs[128 * 64];

  f32x4 acc[4][4] = {};
  const int srow  = t >> 3;
  const int sslot = t & 7;

  for (int k0 = 0; k0 < KDIM; k0 += 64) {
    __syncthreads();
    #pragma unroll
    for (int i = 0; i < 4; ++i) {
      const int row = i * 32 + srow;
      const int cs  = (sslot ^ (row & 7)) * 8;
      gll16(&Wb[(size_t)(n0 + row) * KDIM + k0 + cs],
            (char*)Bs + i * 4096 + wave * 1024);
      gll16(&Xb[(size_t)(m0 + row) * KDIM + k0 + cs],
            (char*)As + i * 4096 + wave * 1024);
    }
    __syncthreads();

    #pragma unroll
    for (int ks = 0; ks < 2; ++ks) {
      bf16x8 af[4], bfr[4];
      #pragma unroll
      for (int mi = 0; mi < 4; ++mi) {
        const int row = wr * 64 + mi * 16 + frow;
        af[mi] = *(const bf16x8*)&As[row * 64 + ((ks * 4 + hi) ^ (frow & 7)) * 8];
      }
      #pragma unroll
      for (int ni = 0; ni < 4; ++ni) {
        const int row = wc * 64 + ni * 16 + frow;
        bfr[ni] = *(const bf16x8*)&Bs[row * 64 + ((ks * 4 + hi) ^ (frow & 7)) * 8];
      }
      #pragma unroll
      for (int mi = 0; mi < 4; ++mi)
        #pragma unroll
        for (int ni = 0; ni < 4; ++ni)
          acc[mi][ni] = __builtin_amdgcn_mfma_f32_16x16x32_bf16(
              af[mi], bfr[ni], acc[mi][ni], 0, 0, 0);
    }
  }

  #pragma unroll
  for (int mi = 0; mi < 4; ++mi)
    #pragma unroll
    for (int ni = 0; ni < 4; ++ni) {
      const int col = n0 + wc * 64 + ni * 16 + frow;
      const float bv = bias[col];
      #pragma unroll
      for (int rr = 0; rr < 4; ++rr) {
        const int row = m0 + wr * 64 + mi * 16 + hi * 4 + rr;
        Yf[(size_t)row * DMODEL + col] = acc[mi][ni][rr] + bv;
      }
    }
}

// ---------------------------------------------------------------------------
// Flash attention, KVBLK=128, KV-split.  grid (NQ/64, NHEAD, BATCH*nsplit).
// Q frags in registers.  K,Vt staged via global_load_lds from LINEAR global
// layouts with XOR-swizzled source addresses; same XOR on frag reads.
// exp2-domain online softmax.
// ---------------------------------------------------------------------------
__global__ __launch_bounds__(256) void attn_fwd(
    const __bf16* __restrict__ Qb, const __bf16* __restrict__ Kb,
    const __bf16* __restrict__ VtG, const float* __restrict__ mask,
    float* __restrict__ Opart, float* __restrict__ ml,
    __bf16* __restrict__ AObf, int nsplit)
{
  const int qt   = blockIdx.x;
  const int h    = blockIdx.y;
  const int b    = blockIdx.z / nsplit;
  const int sp   = blockIdx.z % nsplit;
  const int t    = threadIdx.x;
  const int lane = t & 63;
  const int wave = t >> 6;
  const int frow = lane & 15;
  const int hi   = lane >> 4;

  __shared__ __align__(16) __bf16 Ks[128 * 64];     // [kv][d], slot^=(kv&7)
  __shared__ __align__(16) __bf16 Vts[64 * 128];    // [d][kv], slot^=(d&7)
  __shared__ __align__(16) __bf16 Ps[4][16][136];   // wave-private P tiles
  __shared__ float addm_l[128];

  const float C1 = 0.125f * LOG2E;
  const float CM = 10000.0f * LOG2E;

  // ---- Q fragments: direct global, once ----
  bf16x8 aq0, aq1;
  {
    const __bf16* qp = &Qb[((size_t)(b * NQ + qt * 64 + wave * 16 + frow)) * DMODEL + h * HDIM + hi * 8];
    aq0 = *(const bf16x8*)qp;
    aq1 = *(const bf16x8*)(qp + 32);
  }

  float m_r[4], l_r[4];
  f32x4 oacc[4] = {};
  #pragma unroll
  for (int r = 0; r < 4; ++r) { m_r[r] = -INFINITY; l_r[r] = 0.f; }

  const int schunks = (NS / 128) / nsplit;
  const int sbase   = sp * schunks * 128;
  const size_t kbase = (size_t)b * NS * DMODEL + h * HDIM;
  const size_t vbase = ((size_t)b * NHEAD + h) * HDIM * (size_t)NS;

  const int krow_l = lane >> 3;            // 0..7
  const int kslot_ = lane & 7;
  const int vrow_l = lane >> 4;            // 0..3
  const int vslot_ = lane & 15;

  for (int it = 0; it < schunks; ++it) {
    const int s0 = sbase + it * 128;
    // ---- stage K (128x64) and Vt (64x128): linear global, swizzled source ----
    #pragma unroll
    for (int r4 = 0; r4 < 4; ++r4) {
      const int strip = r4 * 4 + wave;           // 0..15
      const int krow  = strip * 8 + krow_l;      // 0..127
      gll16(&Kb[kbase + (size_t)(s0 + krow) * DMODEL + ((kslot_ ^ (krow & 7)) << 3)],
            (char*)Ks + strip * 1024);
      const int vrow  = strip * 4 + vrow_l;      // 0..63
      gll16(&VtG[vbase + (size_t)vrow * NS + s0 + ((vslot_ ^ (vrow & 7)) << 3)],
            (char*)Vts + strip * 1024);
    }
    if (t < 128) addm_l[t] = (mask[(size_t)b * NS + s0 + t] - 1.0f) * CM;
    __syncthreads();

    // ---- scores: 16 rows x 128 cols per wave ----
    f32x4 sacc[8];
    #pragma unroll
    for (int j = 0; j < 8; ++j) {
      f32x4 z = {};
      const int row = j * 16 + frow;
      bf16x8 b0 = *(const bf16x8*)&Ks[row * 64 + ((hi    ) ^ (frow & 7)) * 8];
      z = __builtin_amdgcn_mfma_f32_16x16x32_bf16(aq0, b0, z, 0, 0, 0);
      bf16x8 b1 = *(const bf16x8*)&Ks[row * 64 + ((4 + hi) ^ (frow & 7)) * 8];
      sacc[j] = __builtin_amdgcn_mfma_f32_16x16x32_bf16(aq1, b1, z, 0, 0, 0);
    }

    // ---- masked online softmax (log2 domain) ----
    float rmax[4] = {-INFINITY, -INFINITY, -INFINITY, -INFINITY};
    #pragma unroll
    for (int j = 0; j < 8; ++j) {
      const float addm = addm_l[j * 16 + frow];
      #pragma unroll
      for (int r = 0; r < 4; ++r) {
        const float s = sacc[j][r] * C1 + addm;
        sacc[j][r] = s;
        rmax[r] = fmaxf(rmax[r], s);
      }
    }
    #pragma unroll
    for (int r = 0; r < 4; ++r) {
      rmax[r] = fmaxf(rmax[r], __shfl_xor(rmax[r], 1));
      rmax[r] = fmaxf(rmax[r], __shfl_xor(rmax[r], 2));
      rmax[r] = fmaxf(rmax[r], __shfl_xor(rmax[r], 4));
      rmax[r] = fmaxf(rmax[r], __shfl_xor(rmax[r], 8));
    }
    float sf[4];
    #pragma unroll
    for (int r = 0; r < 4; ++r) {
      const float mnew = fmaxf(m_r[r], rmax[r]);
      sf[r] = exp2f(m_r[r] - mnew);
      m_r[r] = mnew;
    }
    float rs[4] = {0.f, 0.f, 0.f, 0.f};
    #pragma unroll
    for (int j = 0; j < 8; ++j)
      #pragma unroll
      for (int r = 0; r < 4; ++r) {
        const float e = exp2f(sacc[j][r] - m_r[r]);
        sacc[j][r] = e;
        rs[r] += e;
      }
    #pragma unroll
    for (int r = 0; r < 4; ++r) {
      rs[r] += __shfl_xor(rs[r], 1);
      rs[r] += __shfl_xor(rs[r], 2);
      rs[r] += __shfl_xor(rs[r], 4);
      rs[r] += __shfl_xor(rs[r], 8);
      l_r[r] = l_r[r] * sf[r] + rs[r];
    }
    #pragma unroll
    for (int j = 0; j < 4; ++j)
      #pragma unroll
      for (int r = 0; r < 4; ++r)
        oacc[j][r] *= sf[r];

    // ---- P -> wave-private LDS (same-wave RAW, no barrier) ----
    #pragma unroll
    for (int j = 0; j < 8; ++j)
      #pragma unroll
      for (int r = 0; r < 4; ++r)
        Ps[wave][hi * 4 + r][j * 16 + frow] = (__bf16)sacc[j][r];

    // ---- O += P V  (K=128 over 4 groups) ----
    bf16x8 pa[4];
    #pragma unroll
    for (int g = 0; g < 4; ++g)
      pa[g] = *(const bf16x8*)&Ps[wave][frow][g * 32 + hi * 8];
    #pragma unroll
    for (int jd = 0; jd < 4; ++jd) {
      const int row = jd * 16 + frow;
      #pragma unroll
      for (int g = 0; g < 4; ++g) {
        bf16x8 bv = *(const bf16x8*)&Vts[row * 128 + (((g * 4 + hi) ^ (frow & 7)) << 3)];
        oacc[jd] = __builtin_amdgcn_mfma_f32_16x16x32_bf16(pa[g], bv, oacc[jd], 0, 0, 0);
      }
    }
    __syncthreads();   // all waves done with Ks/Vts before next stage
  }

  // ---- epilogue ----
  if (ml) {
    const int bh = b * NHEAD + h;
    #pragma unroll
    for (int j = 0; j < 4; ++j)
      #pragma unroll
      for (int r = 0; r < 4; ++r) {
        const int q = qt * 64 + wave * 16 + hi * 4 + r;
        Opart[(((size_t)sp * BH + bh) * NQ + q) * HDIM + j * 16 + frow] = oacc[j][r];
      }
    if (frow == 0) {
      #pragma unroll
      for (int r = 0; r < 4; ++r) {
        const int q = qt * 64 + wave * 16 + hi * 4 + r;
        const size_t mo = (((size_t)sp * BH + bh) * NQ + q) * 2;
        ml[mo]     = m_r[r];
        ml[mo + 1] = l_r[r];
      }
    }
  } else {
    #pragma unroll
    for (int j = 0; j < 4; ++j)
      #pragma unroll
      for (int r = 0; r < 4; ++r) {
        const int row = qt * 64 + wave * 16 + hi * 4 + r;
        const int col = h * HDIM + j * 16 + frow;
        AObf[((size_t)(b * NQ + row)) * DMODEL + col] = (__bf16)(oacc[j][r] / l_r[r]);
      }
  }
}

// ---------------------------------------------------------------------------
// Combine split partials -> AObf.  exp2 domain.
// ---------------------------------------------------------------------------
__global__ __launch_bounds__(256) void attn_combine(
    const float* __restrict__ Opart, const float* __restrict__ ml,
    __bf16* __restrict__ AObf, int nsplit)
{
  const int row = blockIdx.x * 4 + (threadIdx.x >> 6);
  const int d   = threadIdx.x & 63;
  const int bh  = row >> 10;
  const int q   = row & (NQ - 1);

  float M = -INFINITY;
  for (int s = 0; s < nsplit; ++s)
    M = fmaxf(M, ml[(((size_t)s * BH + bh) * NQ + q) * 2]);

  float L = 0.f, acc = 0.f;
  for (int s = 0; s < nsplit; ++s) {
    const size_t mo = (((size_t)s * BH + bh) * NQ + q) * 2;
    const float w = exp2f(ml[mo] - M);
    L   += w * ml[mo + 1];
    acc += w * Opart[(((size_t)s * BH + bh) * NQ + q) * HDIM + d];
  }
  const int bb = bh / NHEAD, hh = bh % NHEAD;
  AObf[((size_t)(bb * NQ + q)) * DMODEL + hh * HDIM + d] = (__bf16)(acc / L);
}

// ---------------------------------------------------------------------------
extern "C" void kernel_launch(void* const* d_in, const int* in_sizes, int n_in,
                              void* d_out, int out_size, void* d_ws, size_t ws_size,
                              hipStream_t stream)
{
  const float* query = (const float*)d_in[0];
  const float* key   = (const float*)d_in[1];
  const float* value = (const float*)d_in[2];
  const float* mask  = (const float*)d_in[3];
  const float* Wq    = (const float*)d_in[4];
  const float* Wk    = (const float*)d_in[5];
  const float* Wv    = (const float*)d_in[6];
  const float* Wo    = (const float*)d_in[7];
  const float* bo    = (const float*)d_in[8];
  float* out = (float*)d_out;

  char* ws = (char*)d_ws;
  // workspace layout (bytes), total 61,341,696 (ws proven >= 84.9 MB, round 6):
  //   wb4  bf16 4*768*768    @ 0           (4,718,592)
  //   Xqb  bf16 2048*768     @ 4,718,592   (3,145,728)   ml aliases (786,432)
  //   Xkb  bf16 8192*768     @ 7,864,320   (12,582,912)  Op aliases (25,165,824)
  //   Xvb  bf16 8192*768     @ 20,447,232  (12,582,912)
  //   Qb   bf16 2048*768     @ 33,030,144  (3,145,728)   AObf aliases
  //   Kb   bf16 8192*768     @ 36,175,872  (12,582,912)
  //   VtG  bf16 24*64*4096   @ 48,758,784  (12,582,912)
  const size_t OFF_XQ = 4718592, OFF_XK = 7864320, OFF_XV = 20447232;
  const size_t OFF_QB = 33030144, OFF_KB = 36175872, OFF_VT = 48758784;
  __bf16* wb4  = (__bf16*)(ws);
  __bf16* Xqb  = (__bf16*)(ws + OFF_XQ);
  __bf16* Xkb  = (__bf16*)(ws + OFF_XK);
  __bf16* Xvb  = (__bf16*)(ws + OFF_XV);
  __bf16* Qb   = (__bf16*)(ws + OFF_QB);
  __bf16* AObf = Qb;                        // Qb dead after attn_fwd
  __bf16* Kb   = (__bf16*)(ws + OFF_KB);
  __bf16* VtG  = (__bf16*)(ws + OFF_VT);
  float*  Op   = (float*)(ws + OFF_XK);     // Xkb/Xvb dead after qkvproj
  float*  mlp  = (float*)(ws + OFF_XQ);     // Xqb dead after qkvproj
  const int nsplit = 4;

  const dim3 blk(256);
  convw<<<dim3(288, 4), blk, 0, stream>>>(Wq, Wk, Wv, Wo, wb4);
  convx<<<dim3(3072, 3), blk, 0, stream>>>(query, key, value, Xqb, Xkb, Xvb);
  qkvproj<<<dim3(6, 144), blk, 0, stream>>>(Xqb, Xkb, Xvb, wb4, Qb, Kb, VtG);

  attn_fwd<<<dim3(NQ / 64, NHEAD, BATCH * nsplit), blk, 0, stream>>>(
      Qb, Kb, VtG, mask, Op, mlp, nullptr, nsplit);
  attn_combine<<<dim3((BH * NQ) / 4), blk, 0, stream>>>(Op, mlp, AObf, nsplit);

  outproj<<<dim3(6, 16), blk, 0, stream>>>(AObf, wb4 + 3 * 589824, out, bo);
}